// Round 3
// baseline (514.514 us; speedup 1.0000x reference)
//
#include <hip/hip_runtime.h>

// TopK (K=64) per row, B=4096 x D=16384 fp32.
// out = zeros; out[row, top64 idx] = value.
//
// R5: persistent-block software pipeline. 512 blocks (2/CU, co-resident),
// 8 rows each, ping-pong register buffers (2 x 8 x uint4). Loads for row i+1
// are issued before the compute phases of row i, and all intra-row barriers
// are raw s_barrier + lgkmcnt(0) ONLY (no vmcnt drain), so prefetch loads
// stream during hist/scan/compact/select. R4 was phase-serialized at ~145us
// vs an ~85us BW floor (59%); this overlaps the load stream with compute.
// Tie resolution is inlined into the write pass (single store per address,
// no cross-wave store-ordering hazard, one fewer barrier).
// Algorithm per row: single 2048-bin histogram of the top 11 ordered-uint
// bits -> threshold bin (~55 elems for N(0,1)) -> compact candidates to LDS
// -> O(C^2) exact rank select -> write pass. Ties lowest-index-first.

#define TK_D      16384
#define TK_K      64
#define TK_BLOCK  512
#define TK_NV     8            // uint4 chunks per thread (TK_D/4/TK_BLOCK)
#define TK_GRID   512          // 2 blocks/CU x 256 CU, persistent
#define TK_BINS   2048
#define TK_CAP    1024         // threshold-bin candidate cap (expected ~55)

__device__ __forceinline__ unsigned ord_map(unsigned b) {
    // larger u <=> larger float (handles negatives)
    return b ^ ((unsigned)((int)b >> 31) | 0x80000000u);
}
__device__ __forceinline__ unsigned ord_inv(unsigned u) {
    return u ^ ((unsigned)((int)(~u) >> 31) | 0x80000000u);
}

// LDS-only barrier: orders DS ops across the block WITHOUT draining vmcnt,
// so prefetch global loads stay in flight across phase boundaries.
__device__ __forceinline__ void bar_lds() {
    asm volatile("s_waitcnt lgkmcnt(0)" ::: "memory");
    __builtin_amdgcn_s_barrier();
    asm volatile("" ::: "memory");
}

struct TkShared {
    int      hist[TK_BINS];    // 8 KiB
    int      wsum[8];
    unsigned cu[TK_CAP];       // candidate ordered-uints, 4 KiB
    int      cidx[TK_CAP];     // candidate columns, 4 KiB
    int      bin, rem, cnt, need;
    unsigned T;
};

__device__ __forceinline__ void process_row(uint4 (&b)[TK_NV], int row,
                                            float* __restrict__ out,
                                            TkShared& sh,
                                            int tid, int lane, int wv) {
    // First use of b -> compiler inserts counted vmcnt wait for THIS buffer
    // (later-issued prefetch loads for the other buffer remain outstanding).
    #pragma unroll
    for (int i = 0; i < TK_NV; i++) {
        b[i].x = ord_map(b[i].x); b[i].y = ord_map(b[i].y);
        b[i].z = ord_map(b[i].z); b[i].w = ord_map(b[i].w);
    }
    ((int4*)sh.hist)[tid] = int4{0, 0, 0, 0};          // zero 4 bins/thread
    if (tid == 0) sh.cnt = 0;
    bar_lds();

    // ---- histogram of top-11 ordered bits ----
    #pragma unroll
    for (int i = 0; i < TK_NV; i++) {
        atomicAdd(&sh.hist[b[i].x >> 21], 1);
        atomicAdd(&sh.hist[b[i].y >> 21], 1);
        atomicAdd(&sh.hist[b[i].z >> 21], 1);
        atomicAdd(&sh.hist[b[i].w >> 21], 1);
    }
    bar_lds();

    // ---- hierarchical suffix scan: thread t owns bins 4t..4t+3 ----
    int h0 = sh.hist[4 * tid + 0], h1 = sh.hist[4 * tid + 1];
    int h2 = sh.hist[4 * tid + 2], h3 = sh.hist[4 * tid + 3];
    int local = h0 + h1 + h2 + h3;
    int suf = local;                                   // sum over lanes >= lane
    #pragma unroll
    for (int off = 1; off < 64; off <<= 1) {
        int o = __shfl_down(suf, off);
        if (lane + off < 64) suf += o;
    }
    if (lane == 0) sh.wsum[wv] = suf;
    bar_lds();

    int above = 0;                                     // bins above this wave
    #pragma unroll
    for (int w2 = 0; w2 < 8; w2++)
        if (w2 > wv) above += sh.wsum[w2];
    int a3 = above + (suf - local);                    // strictly above bin 4t+3
    int S3 = a3 + h3, S2 = S3 + h2, S1 = S2 + h1, S0 = S1 + h0;
    if      (S3 >= TK_K && a3 < TK_K) { sh.bin = 4 * tid + 3; sh.rem = TK_K - a3; }
    else if (S2 >= TK_K && S3 < TK_K) { sh.bin = 4 * tid + 2; sh.rem = TK_K - S3; }
    else if (S1 >= TK_K && S2 < TK_K) { sh.bin = 4 * tid + 1; sh.rem = TK_K - S2; }
    else if (S0 >= TK_K && S1 < TK_K) { sh.bin = 4 * tid + 0; sh.rem = TK_K - S1; }
    bar_lds();

    const unsigned binv = (unsigned)sh.bin;
    const int      rem  = sh.rem;                      // 1..64

    // ---- compact threshold-bin candidates into tiny LDS list ----
    #pragma unroll
    for (int i = 0; i < TK_NV; i++) {
        #pragma unroll
        for (int c = 0; c < 4; c++) {
            unsigned u = ((const unsigned*)&b[i])[c];
            if ((u >> 21) == binv) {
                int pos = atomicAdd(&sh.cnt, 1);
                if (pos < TK_CAP) {
                    sh.cu[pos]   = u;
                    sh.cidx[pos] = 4 * (tid + i * TK_BLOCK) + c;
                }
            }
        }
    }
    bar_lds();

    // ---- exact rank select among candidates: T = rem-th largest ----
    const int C = min(sh.cnt, TK_CAP);
    for (int i = tid; i < C; i += TK_BLOCK) {
        unsigned ui = sh.cu[i];
        int abv = 0, eq = 0;
        for (int j = 0; j < C; j++) {
            unsigned uj = sh.cu[j];
            abv += (uj > ui);
            eq  += (uj == ui);
        }
        if (abv < rem && abv + eq >= rem) {            // same-value writers race benignly
            sh.T    = ui;
            sh.need = rem - abv;                       // ties to accept
        }
    }
    bar_lds();

    const unsigned T    = sh.T;
    const int      need = sh.need;
    const float    tval = __uint_as_float(ord_inv(T));

    // ---- write pass with inline tie resolution: one store per address ----
    float4* __restrict__ orow = (float4*)(out + (size_t)row * TK_D);
    #pragma unroll
    for (int i = 0; i < TK_NV; i++) {
        float4 o;
        #pragma unroll
        for (int c = 0; c < 4; c++) {
            unsigned u = ((const unsigned*)&b[i])[c];
            float v = (u > T) ? __uint_as_float(ord_inv(u)) : 0.0f;
            if (u == T) {                              // rare: ~1 lane/row
                int col  = 4 * (tid + i * TK_BLOCK) + c;
                int rank = 0;
                for (int j = 0; j < C; j++)
                    rank += (sh.cu[j] == T && sh.cidx[j] < col);
                v = (rank < need) ? tval : 0.0f;       // lowest-index-first
            }
            ((float*)&o)[c] = v;
        }
        orow[tid + i * TK_BLOCK] = o;
    }
    // no trailing barrier: the next row's first bar_lds orders LDS reuse
    // (any thread must pass it before touching sh.cu/sh.hist again).
}

__launch_bounds__(TK_BLOCK, 4)
__global__ void topk_scatter_kernel(const float* __restrict__ x,
                                    float* __restrict__ out, int nrows) {
    __shared__ TkShared sh;
    const int tid  = threadIdx.x;
    const int lane = tid & 63;
    const int wv   = tid >> 6;
    const int niter = nrows / TK_GRID;                 // 8 for B=4096

    uint4 bufA[TK_NV], bufB[TK_NV];
    int rowA = blockIdx.x;
    {
        const uint4* __restrict__ p = (const uint4*)(x + (size_t)rowA * TK_D);
        #pragma unroll
        for (int i = 0; i < TK_NV; i++) bufA[i] = p[tid + i * TK_BLOCK];
    }
    #pragma unroll 1
    for (int it = 0; it < niter; it += 2) {
        const int rowB = rowA + TK_GRID;
        if (it + 1 < niter) {                          // prefetch row i+1
            const uint4* __restrict__ p = (const uint4*)(x + (size_t)rowB * TK_D);
            #pragma unroll
            for (int i = 0; i < TK_NV; i++) bufB[i] = p[tid + i * TK_BLOCK];
        }
        process_row(bufA, rowA, out, sh, tid, lane, wv);
        if (it + 1 < niter) {
            const int rowA2 = rowB + TK_GRID;
            if (it + 2 < niter) {                      // prefetch row i+2
                const uint4* __restrict__ p = (const uint4*)(x + (size_t)rowA2 * TK_D);
                #pragma unroll
                for (int i = 0; i < TK_NV; i++) bufA[i] = p[tid + i * TK_BLOCK];
            }
            process_row(bufB, rowB, out, sh, tid, lane, wv);
            rowA = rowA2;
        }
    }
}

extern "C" void kernel_launch(void* const* d_in, const int* in_sizes, int n_in,
                              void* d_out, int out_size, void* d_ws, size_t ws_size,
                              hipStream_t stream) {
    const float* x = (const float*)d_in[0];
    float* out = (float*)d_out;
    const int B = in_sizes[0] / TK_D;                  // 4096
    topk_scatter_kernel<<<TK_GRID, TK_BLOCK, 0, stream>>>(x, out, B);
}

// Round 4
// 470.219 us; speedup vs baseline: 1.0942x; 1.0942x over previous
//
#include <hip/hip_runtime.h>

// TopK (K=64) per row, B=4096 x D=16384 fp32.
// out = zeros; out[row, top64 idx] = value.
//
// R6: single-buffer persistent pipeline. R5's double-buffer spilled to
// scratch (VGPR_Count=64 proves SROA failure on the by-ref ping-pong
// arrays). Fix: make the register row die EARLY. The compact phase now
// captures BOTH the threshold-bin candidates AND the <=63 winner values
// (bins strictly above threshold) into LDS, plus a per-thread 32-bit
// coverage mask. After compact, the write pass needs no row data:
//   stream zeros (skipping covered columns) + scatter from LDS lists.
// Streaming and scatter hit disjoint addresses -> no ordering hazard.
// The single 32-VGPR buffer is refilled (prefetch row i+1) right after
// compact; loads stay in flight through select/stream/scatter (LDS-only
// barriers, no vmcnt drain) and are waited on at row i+1's first use.
// Grid: 512 persistent blocks (2/CU), 8 rows each.
// Ties at threshold resolved lowest-index-first (lax.top_k semantics).

#define TK_D      16384
#define TK_K      64
#define TK_BLOCK  512
#define TK_NV     8            // uint4 chunks per thread (TK_D/4/TK_BLOCK)
#define TK_GRID   512          // 2 blocks/CU x 256 CU, persistent
#define TK_BINS   2048
#define TK_CAP    1024         // threshold-bin candidate cap (expected ~55)
#define TK_WCAP   64           // winners cap (count is K - rem <= 63)

__device__ __forceinline__ unsigned ord_map(unsigned b) {
    // larger u <=> larger float (handles negatives)
    return b ^ ((unsigned)((int)b >> 31) | 0x80000000u);
}
__device__ __forceinline__ unsigned ord_inv(unsigned u) {
    return u ^ ((unsigned)((int)(~u) >> 31) | 0x80000000u);
}

// LDS-only barrier: orders DS ops across the block WITHOUT draining vmcnt,
// so prefetch global loads stay in flight across phase boundaries.
__device__ __forceinline__ void bar_lds() {
    asm volatile("s_waitcnt lgkmcnt(0)" ::: "memory");
    __builtin_amdgcn_s_barrier();
    asm volatile("" ::: "memory");
}

__launch_bounds__(TK_BLOCK, 4)
__global__ void topk_scatter_kernel(const float* __restrict__ x,
                                    float* __restrict__ out, int nrows) {
    __shared__ int      sh_hist[TK_BINS];    // 8 KiB
    __shared__ int      sh_wsum[8];
    __shared__ unsigned sh_cu[TK_CAP];       // candidate ordered-uints
    __shared__ int      sh_cidx[TK_CAP];     // candidate columns
    __shared__ unsigned sh_wval[TK_WCAP];    // winner ordered-uints
    __shared__ int      sh_wcol[TK_WCAP];    // winner columns
    __shared__ int      sh_bin, sh_rem, sh_cnt, sh_wcnt, sh_need;
    __shared__ unsigned sh_T;

    const int tid   = threadIdx.x;
    const int lane  = tid & 63;
    const int wv    = tid >> 6;
    const int niter = nrows / TK_GRID;       // 8 for B=4096

    uint4 b[TK_NV];                          // the single row buffer
    {
        const uint4* __restrict__ p = (const uint4*)(x + (size_t)blockIdx.x * TK_D);
        #pragma unroll
        for (int i = 0; i < TK_NV; i++) b[i] = p[tid + i * TK_BLOCK];
    }

    #pragma unroll 1
    for (int it = 0; it < niter; it++) {
        const int row = blockIdx.x + it * TK_GRID;

        // ---- phase 1: ord_map (first use -> waits this row's loads only),
        //      zero hist + counters ----
        #pragma unroll
        for (int i = 0; i < TK_NV; i++) {
            b[i].x = ord_map(b[i].x); b[i].y = ord_map(b[i].y);
            b[i].z = ord_map(b[i].z); b[i].w = ord_map(b[i].w);
        }
        ((int4*)sh_hist)[tid] = int4{0, 0, 0, 0};
        if (tid == 0) { sh_cnt = 0; sh_wcnt = 0; }
        bar_lds();

        // ---- phase 2: histogram of top-11 ordered bits ----
        #pragma unroll
        for (int i = 0; i < TK_NV; i++) {
            atomicAdd(&sh_hist[b[i].x >> 21], 1);
            atomicAdd(&sh_hist[b[i].y >> 21], 1);
            atomicAdd(&sh_hist[b[i].z >> 21], 1);
            atomicAdd(&sh_hist[b[i].w >> 21], 1);
        }
        bar_lds();

        // ---- phase 3: hierarchical suffix scan, pick threshold bin ----
        int h0 = sh_hist[4 * tid + 0], h1 = sh_hist[4 * tid + 1];
        int h2 = sh_hist[4 * tid + 2], h3 = sh_hist[4 * tid + 3];
        int local = h0 + h1 + h2 + h3;
        int suf = local;                     // sum over lanes >= lane
        #pragma unroll
        for (int off = 1; off < 64; off <<= 1) {
            int o = __shfl_down(suf, off);
            if (lane + off < 64) suf += o;
        }
        if (lane == 0) sh_wsum[wv] = suf;
        bar_lds();

        int above = 0;
        #pragma unroll
        for (int w2 = 0; w2 < 8; w2++)
            if (w2 > wv) above += sh_wsum[w2];
        int a3 = above + (suf - local);      // strictly above bin 4t+3
        int S3 = a3 + h3, S2 = S3 + h2, S1 = S2 + h1, S0 = S1 + h0;
        if      (S3 >= TK_K && a3 < TK_K) { sh_bin = 4 * tid + 3; sh_rem = TK_K - a3; }
        else if (S2 >= TK_K && S3 < TK_K) { sh_bin = 4 * tid + 2; sh_rem = TK_K - S3; }
        else if (S1 >= TK_K && S2 < TK_K) { sh_bin = 4 * tid + 1; sh_rem = TK_K - S2; }
        else if (S0 >= TK_K && S1 < TK_K) { sh_bin = 4 * tid + 0; sh_rem = TK_K - S1; }
        bar_lds();

        const unsigned binv = (unsigned)sh_bin;
        const int      rem  = sh_rem;        // 1..64

        // ---- phase 4: compact winners + candidates, build coverage mask.
        //      Row registers DIE here. ----
        unsigned mcov = 0u;
        #pragma unroll
        for (int i = 0; i < TK_NV; i++) {
            #pragma unroll
            for (int c = 0; c < 4; c++) {
                unsigned u  = ((const unsigned*)&b[i])[c];
                unsigned bn = u >> 21;
                if (bn > binv) {             // guaranteed top-K (<=63 of these)
                    int pos = atomicAdd(&sh_wcnt, 1);
                    if (pos < TK_WCAP) {
                        sh_wval[pos] = u;
                        sh_wcol[pos] = 4 * (tid + i * TK_BLOCK) + c;
                    }
                    mcov |= 1u << (4 * i + c);
                } else if (bn == binv) {     // threshold-bin candidate
                    int pos = atomicAdd(&sh_cnt, 1);
                    if (pos < TK_CAP) {
                        sh_cu[pos]   = u;
                        sh_cidx[pos] = 4 * (tid + i * TK_BLOCK) + c;
                        mcov |= 1u << (4 * i + c);
                    }
                }
            }
        }
        bar_lds();

        // counters stable now; capture to regs (tail phases must not re-read
        // LDS scalars that the next row's phase 1 will zero).
        const int C = min(sh_cnt, TK_CAP);
        const int W = min(sh_wcnt, TK_WCAP);

        // ---- phase 5: prefetch next row into the (dead) buffer; loads
        //      stream under select + write + scatter + next hist ----
        if (it + 1 < niter) {
            const uint4* __restrict__ p =
                (const uint4*)(x + (size_t)(row + TK_GRID) * TK_D);
            #pragma unroll
            for (int i = 0; i < TK_NV; i++) b[i] = p[tid + i * TK_BLOCK];
        }

        // ---- phase 6: exact rank select among candidates ----
        for (int i = tid; i < C; i += TK_BLOCK) {
            unsigned ui = sh_cu[i];
            int abv = 0, eq = 0;
            for (int j = 0; j < C; j++) {
                unsigned uj = sh_cu[j];
                abv += (uj > ui);
                eq  += (uj == ui);
            }
            if (abv < rem && abv + eq >= rem) {  // equal-value writers: benign
                sh_T    = ui;
                sh_need = rem - abv;
            }
        }
        bar_lds();

        const unsigned T    = sh_T;          // capture before next-row zeroing
        const int      need = sh_need;
        const float    tval = __uint_as_float(ord_inv(T));

        // ---- phase 7: stream zeros, skipping covered columns ----
        float* const orow = out + (size_t)row * TK_D;
        #pragma unroll
        for (int i = 0; i < TK_NV; i++) {
            const int q = tid + i * TK_BLOCK;
            const unsigned qm = (mcov >> (4 * i)) & 0xFu;
            if (qm == 0u) {
                ((float4*)orow)[q] = float4{0.0f, 0.0f, 0.0f, 0.0f};
            } else {                         // rare: ~127 quads / 4096 per row
                #pragma unroll
                for (int c = 0; c < 4; c++)
                    if (!((qm >> c) & 1u)) orow[4 * q + c] = 0.0f;
            }
        }

        // ---- phase 8: scatter winners + resolved candidates (disjoint from
        //      phase-7 addresses -> no ordering needed) ----
        for (int i = tid; i < W; i += TK_BLOCK)
            orow[sh_wcol[i]] = __uint_as_float(ord_inv(sh_wval[i]));
        for (int i = tid; i < C; i += TK_BLOCK) {
            unsigned u   = sh_cu[i];
            int      col = sh_cidx[i];
            float v = 0.0f;
            if (u > T) {
                v = __uint_as_float(ord_inv(u));
            } else if (u == T) {             // lowest column indices first
                int rank = 0;
                for (int j = 0; j < C; j++)
                    rank += (sh_cu[j] == T && sh_cidx[j] < col);
                if (rank < need) v = tval;
            }
            orow[col] = v;
        }
        // no trailing barrier: next row's phase-1 bar_lds is the rendezvous;
        // its zeroing touches only sh_hist/sh_cnt/sh_wcnt, whose values this
        // tail already captured into registers.
    }
}

extern "C" void kernel_launch(void* const* d_in, const int* in_sizes, int n_in,
                              void* d_out, int out_size, void* d_ws, size_t ws_size,
                              hipStream_t stream) {
    const float* x = (const float*)d_in[0];
    float* out = (float*)d_out;
    const int B = in_sizes[0] / TK_D;        // 4096
    topk_scatter_kernel<<<TK_GRID, TK_BLOCK, 0, stream>>>(x, out, B);
}

// Round 5
// 455.802 us; speedup vs baseline: 1.1288x; 1.0316x over previous
//
#include <hip/hip_runtime.h>

// TopK (K=64) per row, B=4096 x D=16384 fp32.
// out = zeros; out[row, top64 idx] = value.
//
// R7: two-kernel split. R5/R6's fused persistent pipeline never pipelined:
// the scatter/masked-store phases issue a RUNTIME-VARIABLE number of stores,
// so the compiler's s_waitcnt pass cannot emit counted vmcnt(N) across the
// row boundary and degrades to vmcnt(0) -- draining the whole previous row's
// store stream before the next row's compute (measured: 2.3 TB/s, 47% memory
// idle). Instead of fighting for a perfect static pipeline, split into two
// trivially BW-bound kernels:
//   A (select): 1 block/row. load row -> 2048-bin hist of top-11 ordered-uint
//     bits -> suffix scan -> compact winners+candidates -> exact rank select
//     -> emit exactly K (col,val) pairs packed in the first 512 B of the
//     OUTPUT row (no workspace needed; B reads then overwrites them).
//     Read-bound: 256 MB.
//   B (materialize): 1 block/row. read the 64 pairs (drain before any store),
//     build the row in a 64 KiB LDS image (zeros + <=64 scatter -- all
//     register indexing static), stream LDS->global with 8 dwordx4/thread.
//     Write-bound: 256 MB at fill rate.
// Ties at threshold resolved lowest-index-first (lax.top_k semantics).

#define TK_D      16384
#define TK_K      64
#define TK_BLOCK  512
#define TK_NV     8            // uint4 chunks per thread (TK_D/4/TK_BLOCK)
#define TK_BINS   2048
#define TK_CAP    1024         // threshold-bin candidate cap (expected ~55)
#define TK_WCAP   64           // winners cap (W = K - rem <= 63 guaranteed)

__device__ __forceinline__ unsigned ord_map(unsigned b) {
    // larger u <=> larger float (handles negatives)
    return b ^ ((unsigned)((int)b >> 31) | 0x80000000u);
}
__device__ __forceinline__ unsigned ord_inv(unsigned u) {
    return u ^ ((unsigned)((int)(~u) >> 31) | 0x80000000u);
}

// ---------------------------------------------------------------- kernel A
__launch_bounds__(TK_BLOCK, 4)
__global__ void topk_select_kernel(const float* __restrict__ x,
                                   float* __restrict__ out) {
    __shared__ int      sh_hist[TK_BINS];    // 8 KiB
    __shared__ int      sh_wsum[8];
    __shared__ unsigned sh_cu[TK_CAP];       // candidate ordered-uints
    __shared__ int      sh_cidx[TK_CAP];     // candidate columns
    __shared__ unsigned sh_wval[TK_WCAP];    // winner ordered-uints
    __shared__ int      sh_wcol[TK_WCAP];    // winner columns
    __shared__ int      sh_bin, sh_rem, sh_cnt, sh_wcnt, sh_need, sh_emit;
    __shared__ unsigned sh_T;

    const int row  = blockIdx.x;
    const int tid  = threadIdx.x;
    const int lane = tid & 63;
    const int wv   = tid >> 6;

    // coalesced row load -> registers, ord-mapped in place
    uint4 b[TK_NV];
    {
        const uint4* __restrict__ p = (const uint4*)(x + (size_t)row * TK_D);
        #pragma unroll
        for (int i = 0; i < TK_NV; i++) b[i] = p[tid + i * TK_BLOCK];
    }
    ((int4*)sh_hist)[tid] = int4{0, 0, 0, 0};
    if (tid == 0) { sh_cnt = 0; sh_wcnt = 0; sh_emit = 0; }
    #pragma unroll
    for (int i = 0; i < TK_NV; i++) {
        b[i].x = ord_map(b[i].x); b[i].y = ord_map(b[i].y);
        b[i].z = ord_map(b[i].z); b[i].w = ord_map(b[i].w);
    }
    __syncthreads();

    // histogram of top-11 ordered bits
    #pragma unroll
    for (int i = 0; i < TK_NV; i++) {
        atomicAdd(&sh_hist[b[i].x >> 21], 1);
        atomicAdd(&sh_hist[b[i].y >> 21], 1);
        atomicAdd(&sh_hist[b[i].z >> 21], 1);
        atomicAdd(&sh_hist[b[i].w >> 21], 1);
    }
    __syncthreads();

    // hierarchical suffix scan: thread t owns bins 4t..4t+3
    int h0 = sh_hist[4 * tid + 0], h1 = sh_hist[4 * tid + 1];
    int h2 = sh_hist[4 * tid + 2], h3 = sh_hist[4 * tid + 3];
    int local = h0 + h1 + h2 + h3;
    int suf = local;                         // sum over lanes >= lane
    #pragma unroll
    for (int off = 1; off < 64; off <<= 1) {
        int o = __shfl_down(suf, off);
        if (lane + off < 64) suf += o;
    }
    if (lane == 0) sh_wsum[wv] = suf;
    __syncthreads();

    int above = 0;
    #pragma unroll
    for (int w2 = 0; w2 < 8; w2++)
        if (w2 > wv) above += sh_wsum[w2];
    int a3 = above + (suf - local);          // strictly above bin 4t+3
    int S3 = a3 + h3, S2 = S3 + h2, S1 = S2 + h1, S0 = S1 + h0;
    if      (S3 >= TK_K && a3 < TK_K) { sh_bin = 4 * tid + 3; sh_rem = TK_K - a3; }
    else if (S2 >= TK_K && S3 < TK_K) { sh_bin = 4 * tid + 2; sh_rem = TK_K - S3; }
    else if (S1 >= TK_K && S2 < TK_K) { sh_bin = 4 * tid + 1; sh_rem = TK_K - S2; }
    else if (S0 >= TK_K && S1 < TK_K) { sh_bin = 4 * tid + 0; sh_rem = TK_K - S1; }
    __syncthreads();

    const unsigned binv = (unsigned)sh_bin;
    const int      rem  = sh_rem;            // 1..64

    // compact winners (bins > threshold bin) + threshold-bin candidates
    #pragma unroll
    for (int i = 0; i < TK_NV; i++) {
        #pragma unroll
        for (int c = 0; c < 4; c++) {
            unsigned u  = ((const unsigned*)&b[i])[c];
            unsigned bn = u >> 21;
            if (bn > binv) {                 // guaranteed top-K, W <= 63
                int pos = atomicAdd(&sh_wcnt, 1);
                if (pos < TK_WCAP) {
                    sh_wval[pos] = u;
                    sh_wcol[pos] = 4 * (tid + i * TK_BLOCK) + c;
                }
            } else if (bn == binv) {
                int pos = atomicAdd(&sh_cnt, 1);
                if (pos < TK_CAP) {
                    sh_cu[pos]   = u;
                    sh_cidx[pos] = 4 * (tid + i * TK_BLOCK) + c;
                }
            }
        }
    }
    __syncthreads();

    const int C = min(sh_cnt, TK_CAP);
    const int W = min(sh_wcnt, TK_WCAP);

    // exact rank select among candidates: T = rem-th largest
    for (int i = tid; i < C; i += TK_BLOCK) {
        unsigned ui = sh_cu[i];
        int abv = 0, eq = 0;
        for (int j = 0; j < C; j++) {
            unsigned uj = sh_cu[j];
            abv += (uj > ui);
            eq  += (uj == ui);
        }
        if (abv < rem && abv + eq >= rem) {  // equal-value writers: benign race
            sh_T    = ui;
            sh_need = rem - abv;
        }
    }
    __syncthreads();

    const unsigned T    = sh_T;
    const int      need = sh_need;

    // emit exactly K (col,val) pairs into the first 2K floats of the out row.
    // col stored as raw uint bits (bit-cast only, never arithmetic).
    float2* const prow = (float2*)(out + (size_t)row * TK_D);
    for (int i = tid; i < W; i += TK_BLOCK) {
        int s = atomicAdd(&sh_emit, 1);
        prow[s] = float2{__uint_as_float((unsigned)sh_wcol[i]),
                         __uint_as_float(ord_inv(sh_wval[i]))};
    }
    for (int i = tid; i < C; i += TK_BLOCK) {
        unsigned u = sh_cu[i];
        bool take = (u > T);
        if (u == T) {                        // lowest column indices first
            int col = sh_cidx[i], rank = 0;
            for (int j = 0; j < C; j++)
                rank += (sh_cu[j] == T && sh_cidx[j] < col);
            take = (rank < need);
        }
        if (take) {
            int s = atomicAdd(&sh_emit, 1);
            prow[s] = float2{__uint_as_float((unsigned)sh_cidx[i]),
                             __uint_as_float(ord_inv(u))};
        }
    }
}

// ---------------------------------------------------------------- kernel B
__launch_bounds__(TK_BLOCK, 4)
__global__ void topk_write_kernel(float* __restrict__ out) {
    __shared__ float sh_row[TK_D];           // 64 KiB row image
    __shared__ int   sh_col[TK_K];
    __shared__ float sh_val[TK_K];

    const int row = blockIdx.x;
    const int tid = threadIdx.x;
    float* const orow = out + (size_t)row * TK_D;

    // read this row's K pairs (written by kernel A at the row head)
    if (tid < TK_K) {
        float2 pr = ((const float2*)orow)[tid];
        sh_col[tid] = (int)__float_as_uint(pr.x);
        sh_val[tid] = pr.y;
    }
    // zero the LDS row image
    #pragma unroll
    for (int i = 0; i < TK_NV; i++)
        ((float4*)sh_row)[tid + i * TK_BLOCK] = float4{0.f, 0.f, 0.f, 0.f};
    __syncthreads();                         // pair loads drained (vmcnt 0)
                                             // + zeros visible

    // scatter the K values into the image
    if (tid < TK_K) sh_row[sh_col[tid]] = sh_val[tid];
    __syncthreads();

    // stream the finished image to global: static VMEM counts, fire-and-forget
    #pragma unroll
    for (int i = 0; i < TK_NV; i++) {
        float4 v = ((const float4*)sh_row)[tid + i * TK_BLOCK];
        ((float4*)orow)[tid + i * TK_BLOCK] = v;
    }
}

extern "C" void kernel_launch(void* const* d_in, const int* in_sizes, int n_in,
                              void* d_out, int out_size, void* d_ws, size_t ws_size,
                              hipStream_t stream) {
    const float* x = (const float*)d_in[0];
    float* out = (float*)d_out;
    const int B = in_sizes[0] / TK_D;        // 4096
    topk_select_kernel<<<B, TK_BLOCK, 0, stream>>>(x, out);
    topk_write_kernel<<<B, TK_BLOCK, 0, stream>>>(out);
}